// Round 1
// baseline (1657.592 us; speedup 1.0000x reference)
//
#include <hip/hip_runtime.h>
#include <cstdint>
#include <cstddef>

// ---------------- problem constants ----------------
#define BS    4096
#define DIM   768
#define GM    128
#define GN    128
#define COMPS (GM * GN)          // 16384
#define NITER_F 1000.0f
#define ALPHA0  0.3f
#define SIGMA0  64.0f            // max(M,N)/2

// ---------------- workspace layout (bytes) ----------------
#define G_OFF     0UL
#define G_BYTES   ((size_t)COMPS * DIM * 4UL)     // 50,331,648
#define BEST_OFF  (G_OFF + G_BYTES)
#define BEST_BYTES ((size_t)BS * 8UL)             // 32 KB
#define CNT_OFF   (BEST_OFF + BEST_BYTES)
#define CNT_BYTES ((size_t)COMPS * 4UL)           // 64 KB
#define CNTH_OFF  (CNT_OFF + CNT_BYTES)
#define S_OFF     (CNTH_OFF + CNT_BYTES)
#define ETAB_OFF  (S_OFF + CNT_BYTES)             // E is 128x128 floats = 64 KB
#define WN2_OFF   (ETAB_OFF + CNT_BYTES)
#define WS_NEEDED (WN2_OFF + CNT_BYTES)           // ~48.4 MiB

// pack (score, index) so that u64 max == (max score, min index on ties)
__device__ __forceinline__ unsigned long long packScore(float s, int c) {
    unsigned u = __float_as_uint(s);
    u = (u & 0x80000000u) ? ~u : (u | 0x80000000u);   // order-preserving map
    return ((unsigned long long)u << 32) | (unsigned)(~(unsigned)c);
}

// ---------------- 0.5*||w_c||^2 ----------------
__global__ void wn2_kernel(const float* __restrict__ w, float* __restrict__ wn2) {
    const int c = blockIdx.x;
    const float* row = w + (size_t)c * DIM;
    float s = 0.f;
    for (int d = threadIdx.x; d < DIM; d += 64) { float v = row[d]; s += v * v; }
    #pragma unroll
    for (int off = 32; off; off >>= 1) s += __shfl_down(s, off, 64);
    if (threadIdx.x == 0) wn2[c] = 0.5f * s;
}

// ---------------- Gaussian table E[p][r] = exp(-(p-r)^2 / sigma^2) ----------------
__global__ void etab_kernel(const int* __restrict__ itp, float* __restrict__ etab) {
    const int idx = blockIdx.x * 256 + threadIdx.x;    // 0..16383
    const int p = idx >> 7, r = idx & 127;
    const float decay = 1.f - (float)(*itp) / NITER_F;
    const float sig = SIGMA0 * decay;
    const float d = (float)(p - r);
    etab[idx] = expf(-(d * d) / (sig * sig));
}

// ---------------- fused GEMM + argmax:  best_b = argmax_c (x_b.w_c - 0.5||w_c||^2) ----------------
__global__ __launch_bounds__(256) void bmu_kernel(
    const float* __restrict__ x, const float* __restrict__ w,
    const float* __restrict__ wn2, unsigned long long* __restrict__ best) {
    __shared__ float xsT[32][68];   // [k][b], pitch 68 floats = 272 B (16B aligned rows)
    __shared__ float wsT[32][68];   // [k][c]
    __shared__ unsigned long long red[64][16];

    const int tid = threadIdx.x;
    const int tx = tid & 15, ty = tid >> 4;
    const int c0 = blockIdx.x * 64;
    const int b0 = blockIdx.y * 64;
    const int lcol = tid & 31, lrow = tid >> 5;

    float acc[4][4];
    #pragma unroll
    for (int i = 0; i < 4; ++i)
        #pragma unroll
        for (int j = 0; j < 4; ++j) acc[i][j] = 0.f;

    for (int k0 = 0; k0 < DIM; k0 += 32) {
        #pragma unroll
        for (int rr = 0; rr < 8; ++rr) {
            xsT[lcol][lrow + rr * 8] = x[(size_t)(b0 + lrow + rr * 8) * DIM + k0 + lcol];
            wsT[lcol][lrow + rr * 8] = w[(size_t)(c0 + lrow + rr * 8) * DIM + k0 + lcol];
        }
        __syncthreads();
        #pragma unroll
        for (int kk = 0; kk < 32; ++kk) {
            float4 av = *(const float4*)&xsT[kk][ty * 4];
            float4 bv = *(const float4*)&wsT[kk][tx * 4];
            float a_[4] = {av.x, av.y, av.z, av.w};
            float b_[4] = {bv.x, bv.y, bv.z, bv.w};
            #pragma unroll
            for (int i = 0; i < 4; ++i)
                #pragma unroll
                for (int j = 0; j < 4; ++j) acc[i][j] += a_[i] * b_[j];
        }
        __syncthreads();
    }

    float wn[4];
    #pragma unroll
    for (int j = 0; j < 4; ++j) wn[j] = wn2[c0 + tx * 4 + j];

    #pragma unroll
    for (int i = 0; i < 4; ++i) {
        float bsv = acc[i][0] - wn[0];
        int   bc  = c0 + tx * 4;
        #pragma unroll
        for (int j = 1; j < 4; ++j) {
            float s = acc[i][j] - wn[j];
            if (s > bsv) { bsv = s; bc = c0 + tx * 4 + j; }
        }
        red[ty * 4 + i][tx] = packScore(bsv, bc);
    }
    __syncthreads();
    if (tid < 64) {
        unsigned long long m = red[tid][0];
        #pragma unroll
        for (int k = 1; k < 16; ++k) { unsigned long long v = red[tid][k]; if (v > m) m = v; }
        atomicMax(&best[b0 + tid], m);
    }
}

// ---------------- scatter x rows into grid accumulator G + BMU histogram ----------------
__global__ void scatter_kernel(const unsigned long long* __restrict__ best,
                               const float* __restrict__ x,
                               float* __restrict__ G, float* __restrict__ cnt) {
    const int b = blockIdx.x;
    const int c = (int)(~(unsigned)(best[b] & 0xFFFFFFFFULL));
    float* grow = G + (size_t)c * DIM;
    const float* xrow = x + (size_t)b * DIM;
    for (int d = threadIdx.x; d < DIM; d += 256) atomicAdd(&grow[d], xrow[d]);
    if (threadIdx.x == 0) atomicAdd(&cnt[c], 1.0f);
}

// ---------------- strided batched conv pass: out[p,q,d] = sum_r E[p,r] * in[r,q,d] ----------------
__global__ __launch_bounds__(256) void conv_kernel(
    const float* __restrict__ in, float* __restrict__ out, const float* __restrict__ etab,
    long sri, long sqi, long spo, long sqo) {
    __shared__ float EsT[32][68];   // [r][p]
    __shared__ float ins[32][64];   // [r][d]

    const int tid = threadIdx.x;
    const int tx = tid & 15, ty = tid >> 4;
    const int d0 = blockIdx.x * 64;
    const int p0 = blockIdx.y * 64;
    const int q  = blockIdx.z;
    const int lcol = tid & 31, lrow = tid >> 5;
    const int ld = tid & 63,  lr   = tid >> 6;

    float acc[4][4];
    #pragma unroll
    for (int i = 0; i < 4; ++i)
        #pragma unroll
        for (int j = 0; j < 4; ++j) acc[i][j] = 0.f;

    for (int r0 = 0; r0 < 128; r0 += 32) {
        #pragma unroll
        for (int pp = 0; pp < 8; ++pp)
            EsT[lcol][lrow + pp * 8] = etab[(p0 + lrow + pp * 8) * 128 + r0 + lcol];
        #pragma unroll
        for (int rr = 0; rr < 8; ++rr)
            ins[lr + rr * 4][ld] =
                in[(size_t)(r0 + lr + rr * 4) * sri + (size_t)q * sqi + d0 + ld];
        __syncthreads();
        #pragma unroll
        for (int kk = 0; kk < 32; ++kk) {
            float4 av = *(const float4*)&EsT[kk][ty * 4];
            float4 bv = *(const float4*)&ins[kk][tx * 4];
            float a_[4] = {av.x, av.y, av.z, av.w};
            float b_[4] = {bv.x, bv.y, bv.z, bv.w};
            #pragma unroll
            for (int i = 0; i < 4; ++i)
                #pragma unroll
                for (int j = 0; j < 4; ++j) acc[i][j] += a_[i] * b_[j];
        }
        __syncthreads();
    }

    #pragma unroll
    for (int i = 0; i < 4; ++i) {
        float4 v = make_float4(acc[i][0], acc[i][1], acc[i][2], acc[i][3]);
        *(float4*)&out[(size_t)(p0 + ty * 4 + i) * spo + (size_t)q * sqo + d0 + tx * 4] = v;
    }
}

// ---------------- count convolution (separable), tiny ----------------
__global__ void cntconv1(const float* __restrict__ cnt, const float* __restrict__ etab,
                         float* __restrict__ cntH) {
    const int idx = blockIdx.x * 256 + threadIdx.x;  // i*128 + jc
    const int i = idx >> 7, jc = idx & 127;
    float s = 0.f;
    for (int j = 0; j < 128; ++j) s += etab[jc * 128 + j] * cnt[i * 128 + j];
    cntH[idx] = s;
}
__global__ void cntconv2(const float* __restrict__ cntH, const float* __restrict__ etab,
                         float* __restrict__ S) {
    const int idx = blockIdx.x * 256 + threadIdx.x;  // ic*128 + jc
    const int ic = idx >> 7, jc = idx & 127;
    float s = 0.f;
    for (int i = 0; i < 128; ++i) s += etab[ic * 128 + i] * cntH[i * 128 + jc];
    S[idx] = s;
}

// ---------------- epilogue: out = w*(1 - alpha*S[c]) + alpha*T ----------------
__global__ void final_kernel(const float* __restrict__ w, const float* __restrict__ T,
                             const float* __restrict__ S, const int* __restrict__ itp,
                             float* __restrict__ out) {
    const size_t v = (size_t)blockIdx.x * 256 + threadIdx.x;  // float4 index
    const size_t e = v * 4;
    const int c = (int)(e / DIM);
    const float alpha = ALPHA0 * (1.f - (float)(*itp) / NITER_F);
    const float sc = 1.f - alpha * S[c];
    const float4 wv = *(const float4*)(w + e);
    const float4 tv = *(const float4*)(T + e);
    float4 o;
    o.x = wv.x * sc + alpha * tv.x;
    o.y = wv.y * sc + alpha * tv.y;
    o.z = wv.z * sc + alpha * tv.z;
    o.w = wv.w * sc + alpha * tv.w;
    *(float4*)(out + e) = o;
}

extern "C" void kernel_launch(void* const* d_in, const int* in_sizes, int n_in,
                              void* d_out, int out_size, void* d_ws, size_t ws_size,
                              hipStream_t stream) {
    const float* x  = (const float*)d_in[0];   // [4096, 768]
    const float* w  = (const float*)d_in[1];   // [16384, 768]
    const int* itp  = (const int*)d_in[2];     // scalar it
    float* out = (float*)d_out;                // [16384, 768]
    char* ws = (char*)d_ws;

    float* G    = (float*)(ws + G_OFF);
    unsigned long long* best = (unsigned long long*)(ws + BEST_OFF);
    float* cnt  = (float*)(ws + CNT_OFF);
    float* cntH = (float*)(ws + CNTH_OFF);
    float* S    = (float*)(ws + S_OFF);
    float* etab = (float*)(ws + ETAB_OFF);
    float* wn2  = (float*)(ws + WN2_OFF);

    // zero G + best + cnt (ws is re-poisoned 0xAA before every call)
    hipMemsetAsync(ws, 0, CNT_OFF + CNT_BYTES, stream);

    wn2_kernel<<<COMPS, 64, 0, stream>>>(w, wn2);
    etab_kernel<<<COMPS / 256, 256, 0, stream>>>(itp, etab);

    bmu_kernel<<<dim3(COMPS / 64, BS / 64), 256, 0, stream>>>(x, w, wn2, best);
    scatter_kernel<<<BS, 256, 0, stream>>>(best, x, G, cnt);

    // pass A: H[i, jc, d] = sum_j E[jc,j] G[i,j,d]        (G -> d_out)
    conv_kernel<<<dim3(DIM / 64, 2, 128), 256, 0, stream>>>(
        G, out, etab, 768L, 98304L, 768L, 98304L);
    // pass B: T[ic*128+jc, d] = sum_i E[ic,i] H[i, jc, d] (d_out -> G)
    conv_kernel<<<dim3(DIM / 64, 2, 128), 256, 0, stream>>>(
        out, G, etab, 98304L, 768L, 98304L, 768L);

    cntconv1<<<COMPS / 256, 256, 0, stream>>>(cnt, etab, cntH);
    cntconv2<<<COMPS / 256, 256, 0, stream>>>(cntH, etab, S);

    final_kernel<<<(COMPS * DIM / 4) / 256, 256, 0, stream>>>(w, G, S, itp, out);
}

// Round 2
// 421.802 us; speedup vs baseline: 3.9298x; 3.9298x over previous
//
#include <hip/hip_runtime.h>
#include <cstdint>
#include <cstddef>

// ---------------- problem constants ----------------
#define BS    4096
#define DIM   768
#define GM    128
#define GN    128
#define COMPS (GM * GN)          // 16384
#define NITER_F 1000.0f
#define ALPHA0  0.3f
#define SIGMA0  64.0f            // max(M,N)/2

typedef _Float16 half8  __attribute__((ext_vector_type(8)));
typedef _Float16 half4v __attribute__((ext_vector_type(4)));
typedef float    floatx4 __attribute__((ext_vector_type(4)));

// ---------------- workspace layout (bytes) ----------------
// G region [0, 48MB) is ALSO used (aliased) for the f16 copies xh/wh:
//   xh at +0 (6.3MB), wh at +8MB (25.2MB). bmu reads them; G is zeroed and
//   written only AFTER bmu in stream order, so the alias is safe.
#define G_OFF     0UL
#define G_BYTES   ((size_t)COMPS * DIM * 4UL)     // 50,331,648
#define XH_OFF    0UL
#define WH_OFF    (8UL * 1024UL * 1024UL)
#define BEST_OFF  (G_OFF + G_BYTES)
#define BEST_BYTES ((size_t)BS * 8UL)             // 32 KB
#define CNT_OFF   (BEST_OFF + BEST_BYTES)
#define CNT_BYTES ((size_t)COMPS * 4UL)           // 64 KB
#define CNTH_OFF  (CNT_OFF + CNT_BYTES)
#define S_OFF     (CNTH_OFF + CNT_BYTES)
#define ETAB_OFF  (S_OFF + CNT_BYTES)
#define WN2_OFF   (ETAB_OFF + CNT_BYTES)

#define GPTR(p) ((const __attribute__((address_space(1))) void*)(p))
#define LPTR(p) ((__attribute__((address_space(3))) void*)(p))

// pack (score, index) so that u64 max == (max score, min index on ties)
__device__ __forceinline__ unsigned long long packScore(float s, int c) {
    unsigned u = __float_as_uint(s);
    u = (u & 0x80000000u) ? ~u : (u | 0x80000000u);   // order-preserving map
    return ((unsigned long long)u << 32) | (unsigned)(~(unsigned)c);
}

__device__ __forceinline__ unsigned long long shfl_xor_u64(unsigned long long v, int m) {
    unsigned lo = (unsigned)v, hi = (unsigned)(v >> 32);
    lo = (unsigned)__shfl_xor((int)lo, m, 64);
    hi = (unsigned)__shfl_xor((int)hi, m, 64);
    return ((unsigned long long)hi << 32) | lo;
}

// ---------------- fp32 -> fp16 convert (4 elems/thread) ----------------
__global__ void cvt_kernel(const float* __restrict__ src, _Float16* __restrict__ dst, int n4) {
    int i = blockIdx.x * 256 + threadIdx.x;
    if (i >= n4) return;
    float4 v = ((const float4*)src)[i];
    half4v h;
    h[0] = (_Float16)v.x; h[1] = (_Float16)v.y;
    h[2] = (_Float16)v.z; h[3] = (_Float16)v.w;
    ((half4v*)dst)[i] = h;
}

// ---------------- 0.5*||w_c||^2 (fp32-exact) ----------------
__global__ void wn2_kernel(const float* __restrict__ w, float* __restrict__ wn2) {
    const int c = blockIdx.x;
    const float* row = w + (size_t)c * DIM;
    float s = 0.f;
    for (int d = threadIdx.x; d < DIM; d += 64) { float v = row[d]; s += v * v; }
    #pragma unroll
    for (int off = 32; off; off >>= 1) s += __shfl_down(s, off, 64);
    if (threadIdx.x == 0) wn2[c] = 0.5f * s;
}

// ---------------- Gaussian table E[p][r] = exp(-(p-r)^2 / sigma^2) ----------------
__global__ void etab_kernel(const int* __restrict__ itp, float* __restrict__ etab) {
    const int idx = blockIdx.x * 256 + threadIdx.x;    // 0..16383
    const int p = idx >> 7, r = idx & 127;
    const float decay = 1.f - (float)(*itp) / NITER_F;
    const float sig = SIGMA0 * decay;
    const float d = (float)(p - r);
    etab[idx] = expf(-(d * d) / (sig * sig));
}

// ---------------- MFMA BMU: best_b = argmax_c (x_b.w_c - 0.5||w_c||^2) ----------------
// 128x128 tile, BK=32, v_mfma_f32_16x16x32_f16, 4 waves in 2x2 quadrants.
__global__ __launch_bounds__(256) void bmu_kernel(
    const _Float16* __restrict__ xh, const _Float16* __restrict__ wh,
    const float* __restrict__ wn2, unsigned long long* __restrict__ best) {
    __shared__ _Float16 xs[128 * 32];    // [row][k] row-major, 64B rows
    __shared__ _Float16 wsd[128 * 32];
    __shared__ unsigned long long red[128];

    const int tid  = threadIdx.x;
    const int wv   = tid >> 6;
    const int lane = tid & 63;
    const int c0 = blockIdx.x * 128;
    const int b0 = blockIdx.y * 128;

    if (tid < 128) red[tid] = 0ULL;

    floatx4 acc[4][4];
    #pragma unroll
    for (int i = 0; i < 4; ++i)
        #pragma unroll
        for (int j = 0; j < 4; ++j) acc[i][j] = (floatx4){0.f, 0.f, 0.f, 0.f};

    const int lrow = lane >> 2;          // 0..15 (row within 16-row sub-chunk)
    const int lk   = (lane & 3) * 8;     // k element offset 0/8/16/24
    const int q    = lane >> 4;          // 0..3 (k-quad for MFMA frag)
    const int l15  = lane & 15;
    const int mrow = (wv >> 1) * 64;     // wave's b-quadrant offset
    const int ncol = (wv & 1) * 64;      // wave's c-quadrant offset

    for (int k0 = 0; k0 < DIM; k0 += 32) {
        #pragma unroll
        for (int s = 0; s < 2; ++s) {
            const int sub = 2 * wv + s;                  // 0..7
            const _Float16* gx = xh + (size_t)(b0 + sub * 16 + lrow) * DIM + k0 + lk;
            __builtin_amdgcn_global_load_lds(GPTR(gx), LPTR(xs + sub * 512), 16, 0, 0);
            const _Float16* gw = wh + (size_t)(c0 + sub * 16 + lrow) * DIM + k0 + lk;
            __builtin_amdgcn_global_load_lds(GPTR(gw), LPTR(wsd + sub * 512), 16, 0, 0);
        }
        __syncthreads();   // compiler emits vmcnt(0) drain before barrier

        half8 af[4], bf[4];
        #pragma unroll
        for (int i = 0; i < 4; ++i)
            af[i] = *(const half8*)(xs + (mrow + i * 16 + l15) * 32 + q * 8);
        #pragma unroll
        for (int j = 0; j < 4; ++j)
            bf[j] = *(const half8*)(wsd + (ncol + j * 16 + l15) * 32 + q * 8);
        #pragma unroll
        for (int i = 0; i < 4; ++i)
            #pragma unroll
            for (int j = 0; j < 4; ++j)
                acc[i][j] = __builtin_amdgcn_mfma_f32_16x16x32_f16(af[i], bf[j], acc[i][j], 0, 0, 0);
        __syncthreads();
    }

    // epilogue: argmax over this block's 128 c for each of 128 b
    float wnj[4];
    #pragma unroll
    for (int j = 0; j < 4; ++j) wnj[j] = wn2[c0 + ncol + j * 16 + l15];

    #pragma unroll
    for (int i = 0; i < 4; ++i) {
        #pragma unroll
        for (int r = 0; r < 4; ++r) {
            unsigned long long m = 0ULL;
            #pragma unroll
            for (int j = 0; j < 4; ++j) {
                float s = acc[i][j][r] - wnj[j];
                unsigned long long p = packScore(s, c0 + ncol + j * 16 + l15);
                if (p > m) m = p;
            }
            // reduce across the 16 c-lanes (same b within each lane>>4 group)
            #pragma unroll
            for (int msk = 1; msk <= 8; msk <<= 1) {
                unsigned long long o = shfl_xor_u64(m, msk);
                if (o > m) m = o;
            }
            if (l15 == 0)
                atomicMax(&red[mrow + i * 16 + q * 4 + r], m);
        }
    }
    __syncthreads();
    if (tid < 128) atomicMax(&best[b0 + tid], red[tid]);
}

// ---------------- scatter x rows into grid accumulator G + BMU histogram ----------------
__global__ void scatter_kernel(const unsigned long long* __restrict__ best,
                               const float* __restrict__ x,
                               float* __restrict__ G, float* __restrict__ cnt) {
    const int b = blockIdx.x;
    const int c = (int)(~(unsigned)(best[b] & 0xFFFFFFFFULL));
    float* grow = G + (size_t)c * DIM;
    const float* xrow = x + (size_t)b * DIM;
    for (int d = threadIdx.x; d < DIM; d += 256) atomicAdd(&grow[d], xrow[d]);
    if (threadIdx.x == 0) atomicAdd(&cnt[c], 1.0f);
}

// ---------------- strided batched conv pass: out[p,q,d] = sum_r E[p,r] * in[r,q,d] ----------------
__global__ __launch_bounds__(256) void conv_kernel(
    const float* __restrict__ in, float* __restrict__ out, const float* __restrict__ etab,
    long sri, long sqi, long spo, long sqo) {
    __shared__ float EsT[32][68];   // [r][p]
    __shared__ float ins[32][64];   // [r][d]

    const int tid = threadIdx.x;
    const int tx = tid & 15, ty = tid >> 4;
    const int d0 = blockIdx.x * 64;
    const int p0 = blockIdx.y * 64;
    const int q  = blockIdx.z;
    const int lcol = tid & 31, lrow = tid >> 5;
    const int ld = tid & 63,  lr   = tid >> 6;

    float acc[4][4];
    #pragma unroll
    for (int i = 0; i < 4; ++i)
        #pragma unroll
        for (int j = 0; j < 4; ++j) acc[i][j] = 0.f;

    for (int r0 = 0; r0 < 128; r0 += 32) {
        #pragma unroll
        for (int pp = 0; pp < 8; ++pp)
            EsT[lcol][lrow + pp * 8] = etab[(p0 + lrow + pp * 8) * 128 + r0 + lcol];
        #pragma unroll
        for (int rr = 0; rr < 8; ++rr)
            ins[lr + rr * 4][ld] =
                in[(size_t)(r0 + lr + rr * 4) * sri + (size_t)q * sqi + d0 + ld];
        __syncthreads();
        #pragma unroll
        for (int kk = 0; kk < 32; ++kk) {
            float4 av = *(const float4*)&EsT[kk][ty * 4];
            float4 bv = *(const float4*)&ins[kk][tx * 4];
            float a_[4] = {av.x, av.y, av.z, av.w};
            float b_[4] = {bv.x, bv.y, bv.z, bv.w};
            #pragma unroll
            for (int i = 0; i < 4; ++i)
                #pragma unroll
                for (int j = 0; j < 4; ++j) acc[i][j] += a_[i] * b_[j];
        }
        __syncthreads();
    }

    #pragma unroll
    for (int i = 0; i < 4; ++i) {
        float4 v = make_float4(acc[i][0], acc[i][1], acc[i][2], acc[i][3]);
        *(float4*)&out[(size_t)(p0 + ty * 4 + i) * spo + (size_t)q * sqo + d0 + tx * 4] = v;
    }
}

// ---------------- count convolution (separable), tiny ----------------
__global__ void cntconv1(const float* __restrict__ cnt, const float* __restrict__ etab,
                         float* __restrict__ cntH) {
    const int idx = blockIdx.x * 256 + threadIdx.x;  // i*128 + jc
    const int i = idx >> 7, jc = idx & 127;
    float s = 0.f;
    for (int j = 0; j < 128; ++j) s += etab[jc * 128 + j] * cnt[i * 128 + j];
    cntH[idx] = s;
}
__global__ void cntconv2(const float* __restrict__ cntH, const float* __restrict__ etab,
                         float* __restrict__ S) {
    const int idx = blockIdx.x * 256 + threadIdx.x;  // ic*128 + jc
    const int ic = idx >> 7, jc = idx & 127;
    float s = 0.f;
    for (int i = 0; i < 128; ++i) s += etab[ic * 128 + i] * cntH[i * 128 + jc];
    S[idx] = s;
}

// ---------------- epilogue: out = w*(1 - alpha*S[c]) + alpha*T ----------------
__global__ void final_kernel(const float* __restrict__ w, const float* __restrict__ T,
                             const float* __restrict__ S, const int* __restrict__ itp,
                             float* __restrict__ out) {
    const size_t v = (size_t)blockIdx.x * 256 + threadIdx.x;  // float4 index
    const size_t e = v * 4;
    const int c = (int)(e / DIM);
    const float alpha = ALPHA0 * (1.f - (float)(*itp) / NITER_F);
    const float sc = 1.f - alpha * S[c];
    const float4 wv = *(const float4*)(w + e);
    const float4 tv = *(const float4*)(T + e);
    float4 o;
    o.x = wv.x * sc + alpha * tv.x;
    o.y = wv.y * sc + alpha * tv.y;
    o.z = wv.z * sc + alpha * tv.z;
    o.w = wv.w * sc + alpha * tv.w;
    *(float4*)(out + e) = o;
}

extern "C" void kernel_launch(void* const* d_in, const int* in_sizes, int n_in,
                              void* d_out, int out_size, void* d_ws, size_t ws_size,
                              hipStream_t stream) {
    const float* x  = (const float*)d_in[0];   // [4096, 768]
    const float* w  = (const float*)d_in[1];   // [16384, 768]
    const int* itp  = (const int*)d_in[2];     // scalar it
    float* out = (float*)d_out;                // [16384, 768]
    char* ws = (char*)d_ws;

    float* G    = (float*)(ws + G_OFF);
    _Float16* xh = (_Float16*)(ws + XH_OFF);   // aliases G (dead before G is written)
    _Float16* wh = (_Float16*)(ws + WH_OFF);   // aliases G
    unsigned long long* best = (unsigned long long*)(ws + BEST_OFF);
    float* cnt  = (float*)(ws + CNT_OFF);
    float* cntH = (float*)(ws + CNTH_OFF);
    float* S    = (float*)(ws + S_OFF);
    float* etab = (float*)(ws + ETAB_OFF);
    float* wn2  = (float*)(ws + WN2_OFF);

    // zero best + cnt up front (contiguous)
    hipMemsetAsync(ws + BEST_OFF, 0, BEST_BYTES + CNT_BYTES, stream);

    cvt_kernel<<<(BS * DIM / 4 + 255) / 256, 256, 0, stream>>>(x, xh, BS * DIM / 4);
    cvt_kernel<<<(COMPS * DIM / 4 + 255) / 256, 256, 0, stream>>>(w, wh, COMPS * DIM / 4);
    wn2_kernel<<<COMPS, 64, 0, stream>>>(w, wn2);
    etab_kernel<<<COMPS / 256, 256, 0, stream>>>(itp, etab);

    bmu_kernel<<<dim3(COMPS / 128, BS / 128), 256, 0, stream>>>(xh, wh, wn2, best);

    // xh/wh now dead -> zero G (stream-ordered after bmu), then scatter
    hipMemsetAsync(ws + G_OFF, 0, G_BYTES, stream);
    scatter_kernel<<<BS, 256, 0, stream>>>(best, x, G, cnt);

    // pass A: H[i, jc, d] = sum_j E[jc,j] G[i,j,d]        (G -> d_out)
    conv_kernel<<<dim3(DIM / 64, 2, 128), 256, 0, stream>>>(
        G, out, etab, 768L, 98304L, 768L, 98304L);
    // pass B: T[ic*128+jc, d] = sum_i E[ic,i] H[i, jc, d] (d_out -> G)
    conv_kernel<<<dim3(DIM / 64, 2, 128), 256, 0, stream>>>(
        out, G, etab, 98304L, 768L, 98304L, 768L);

    cntconv1<<<COMPS / 256, 256, 0, stream>>>(cnt, etab, cntH);
    cntconv2<<<COMPS / 256, 256, 0, stream>>>(cntH, etab, S);

    final_kernel<<<(COMPS * DIM / 4) / 256, 256, 0, stream>>>(w, G, S, itp, out);
}

// Round 3
// 360.665 us; speedup vs baseline: 4.5959x; 1.1695x over previous
//
#include <hip/hip_runtime.h>
#include <cstdint>
#include <cstddef>

// ---------------- problem constants ----------------
#define BS    4096
#define DIM   768
#define DH    384                 // d-half width
#define GM    128
#define GN    128
#define COMPS (GM * GN)          // 16384
#define NITER_F 1000.0f
#define ALPHA0  0.3f
#define SIGMA0  64.0f            // max(M,N)/2

typedef _Float16 half8  __attribute__((ext_vector_type(8)));
typedef _Float16 half4v __attribute__((ext_vector_type(4)));
typedef _Float16 half2v __attribute__((ext_vector_type(2)));
typedef float    floatx4 __attribute__((ext_vector_type(4)));

// ---------------- workspace layout (bytes), proven ws >= 50.7MB ----------------
// Phase 1 (pre-bmu): xh fp16 @0 (6.3MB), wh fp16 @8MB (25.2MB), etab_h @44MB.
// Phase 2 (post-bmu): G-half fp32 @0 (24MB), H-half fp16 @26MB (12.6MB).
// Tails at >=50.33MB: best, cnt, cntH, S, etab(fp32), wn2.
#define XH_OFF    0UL
#define WH_OFF    (8UL * 1024UL * 1024UL)
#define GQ_OFF    0UL
#define GQ_BYTES  ((size_t)COMPS * DH * 4UL)      // 25,165,824
#define HQ_OFF    (26UL * 1024UL * 1024UL)
#define ETABH_OFF (44UL * 1024UL * 1024UL)        // 32KB fp16
#define BEST_OFF  ((size_t)COMPS * DIM * 4UL)     // 50,331,648
#define BEST_BYTES ((size_t)BS * 8UL)             // 32 KB
#define CNT_OFF   (BEST_OFF + BEST_BYTES)
#define CNT_BYTES ((size_t)COMPS * 4UL)           // 64 KB
#define CNTH_OFF  (CNT_OFF + CNT_BYTES)
#define S_OFF     (CNTH_OFF + CNT_BYTES)
#define ETAB_OFF  (S_OFF + CNT_BYTES)
#define WN2_OFF   (ETAB_OFF + CNT_BYTES)

#define GPTR(p) ((const __attribute__((address_space(1))) void*)(p))
#define LPTR(p) ((__attribute__((address_space(3))) void*)(p))

// pack (score, index) so that u64 max == (max score, min index on ties)
__device__ __forceinline__ unsigned long long packScore(float s, int c) {
    unsigned u = __float_as_uint(s);
    u = (u & 0x80000000u) ? ~u : (u | 0x80000000u);   // order-preserving map
    return ((unsigned long long)u << 32) | (unsigned)(~(unsigned)c);
}

__device__ __forceinline__ unsigned long long shfl_xor_u64(unsigned long long v, int m) {
    unsigned lo = (unsigned)v, hi = (unsigned)(v >> 32);
    lo = (unsigned)__shfl_xor((int)lo, m, 64);
    hi = (unsigned)__shfl_xor((int)hi, m, 64);
    return ((unsigned long long)hi << 32) | lo;
}

// ---------------- fp32 -> fp16 convert (x) ----------------
__global__ void cvt_kernel(const float* __restrict__ src, _Float16* __restrict__ dst, int n4) {
    int i = blockIdx.x * 256 + threadIdx.x;
    if (i >= n4) return;
    float4 v = ((const float4*)src)[i];
    half4v h;
    h[0] = (_Float16)v.x; h[1] = (_Float16)v.y;
    h[2] = (_Float16)v.z; h[3] = (_Float16)v.w;
    ((half4v*)dst)[i] = h;
}

// ---------------- w: fp32->fp16 convert fused with 0.5*||w_c||^2 ----------------
__global__ __launch_bounds__(192) void cvtw_wn2_kernel(
    const float* __restrict__ w, _Float16* __restrict__ wh, float* __restrict__ wn2) {
    const int c = blockIdx.x;
    const int t = threadIdx.x;                   // 0..191 (one float4 each)
    const size_t i4 = (size_t)c * 192 + t;
    float4 v = ((const float4*)w)[i4];
    half4v h;
    h[0] = (_Float16)v.x; h[1] = (_Float16)v.y;
    h[2] = (_Float16)v.z; h[3] = (_Float16)v.w;
    ((half4v*)wh)[i4] = h;
    float s = v.x * v.x + v.y * v.y + v.z * v.z + v.w * v.w;
    #pragma unroll
    for (int off = 32; off; off >>= 1) s += __shfl_down(s, off, 64);
    __shared__ float p[3];
    if ((t & 63) == 0) p[t >> 6] = s;
    __syncthreads();
    if (t == 0) wn2[c] = 0.5f * (p[0] + p[1] + p[2]);
}

// ---------------- Gaussian table E[p][r] (fp32 + fp16) ----------------
__global__ void etab_kernel(const int* __restrict__ itp, float* __restrict__ etab,
                            _Float16* __restrict__ etab_h) {
    const int idx = blockIdx.x * 256 + threadIdx.x;    // 0..16383
    const int p = idx >> 7, r = idx & 127;
    const float decay = 1.f - (float)(*itp) / NITER_F;
    const float sig = SIGMA0 * decay;
    const float d = (float)(p - r);
    const float v = expf(-(d * d) / (sig * sig));
    etab[idx] = v;
    etab_h[idx] = (_Float16)v;
}

// ---------------- MFMA BMU: best_b = argmax_c (x_b.w_c - 0.5||w_c||^2) ----------------
// 128x128 tile, BK=32, v_mfma_f32_16x16x32_f16, XOR-swizzled LDS quads.
__global__ __launch_bounds__(256) void bmu_kernel(
    const _Float16* __restrict__ xh, const _Float16* __restrict__ wh,
    const float* __restrict__ wn2, unsigned long long* __restrict__ best) {
    __shared__ _Float16 xs[128 * 32];    // [row][quad-swizzled k], 64B rows
    __shared__ _Float16 wsd[128 * 32];
    __shared__ unsigned long long red[128];

    const int tid  = threadIdx.x;
    const int wv   = tid >> 6;
    const int lane = tid & 63;
    const int c0 = blockIdx.x * 128;
    const int b0 = blockIdx.y * 128;

    if (tid < 128) red[tid] = 0ULL;

    floatx4 acc[4][4];
    #pragma unroll
    for (int i = 0; i < 4; ++i)
        #pragma unroll
        for (int j = 0; j < 4; ++j) acc[i][j] = (floatx4){0.f, 0.f, 0.f, 0.f};

    const int rr   = lane >> 2;              // staging row within 16-row sub-chunk
    const int pq   = lane & 3;               // LDS quad position (fixed by HW lane map)
    const int kk   = pq ^ ((rr >> 1) & 3);   // swizzled global k-chunk
    const int lk   = kk * 8;
    const int q    = lane >> 4;              // MFMA k-quad
    const int l15  = lane & 15;
    const int mrow = (wv >> 1) * 64;
    const int ncol = (wv & 1) * 64;

    for (int k0 = 0; k0 < DIM; k0 += 32) {
        #pragma unroll
        for (int s = 0; s < 2; ++s) {
            const int sub = 2 * wv + s;                  // 0..7
            const _Float16* gx = xh + (size_t)(b0 + sub * 16 + rr) * DIM + k0 + lk;
            __builtin_amdgcn_global_load_lds(GPTR(gx), LPTR(xs + sub * 512), 16, 0, 0);
            const _Float16* gw = wh + (size_t)(c0 + sub * 16 + rr) * DIM + k0 + lk;
            __builtin_amdgcn_global_load_lds(GPTR(gw), LPTR(wsd + sub * 512), 16, 0, 0);
        }
        __syncthreads();

        half8 af[4], bf[4];
        #pragma unroll
        for (int i = 0; i < 4; ++i) {
            const int row = mrow + i * 16 + l15;
            af[i] = *(const half8*)(xs + row * 32 + (q ^ ((row >> 1) & 3)) * 8);
        }
        #pragma unroll
        for (int j = 0; j < 4; ++j) {
            const int row = ncol + j * 16 + l15;
            bf[j] = *(const half8*)(wsd + row * 32 + (q ^ ((row >> 1) & 3)) * 8);
        }
        #pragma unroll
        for (int i = 0; i < 4; ++i)
            #pragma unroll
            for (int j = 0; j < 4; ++j)
                acc[i][j] = __builtin_amdgcn_mfma_f32_16x16x32_f16(af[i], bf[j], acc[i][j], 0, 0, 0);
        __syncthreads();
    }

    float wnj[4];
    #pragma unroll
    for (int j = 0; j < 4; ++j) wnj[j] = wn2[c0 + ncol + j * 16 + l15];

    #pragma unroll
    for (int i = 0; i < 4; ++i) {
        #pragma unroll
        for (int r = 0; r < 4; ++r) {
            unsigned long long m = 0ULL;
            #pragma unroll
            for (int j = 0; j < 4; ++j) {
                float s = acc[i][j][r] - wnj[j];
                unsigned long long p = packScore(s, c0 + ncol + j * 16 + l15);
                if (p > m) m = p;
            }
            #pragma unroll
            for (int msk = 1; msk <= 8; msk <<= 1) {
                unsigned long long o = shfl_xor_u64(m, msk);
                if (o > m) m = o;
            }
            if (l15 == 0)
                atomicMax(&red[mrow + i * 16 + q * 4 + r], m);
        }
    }
    __syncthreads();
    if (tid < 128) atomicMax(&best[b0 + tid], red[tid]);
}

// ---------------- scatter x half-rows into compact G-half + histogram ----------------
__global__ void scatter_kernel(const unsigned long long* __restrict__ best,
                               const float* __restrict__ x,
                               float* __restrict__ Gq, float* __restrict__ cnt,
                               int h, int addcnt) {
    const int b = blockIdx.x;
    const int c = (int)(~(unsigned)(best[b] & 0xFFFFFFFFULL));
    float* gr = Gq + (size_t)c * DH;
    const float* xr = x + (size_t)b * DIM + h * DH;
    for (int d = threadIdx.x; d < DH; d += 128) atomicAdd(&gr[d], xr[d]);
    if (threadIdx.x == 0 && addcnt) atomicAdd(&cnt[c], 1.0f);
}

// ---------------- conv pass A (MFMA): H[i,jc,d] = sum_j E[jc,j] * Gq[i*128+j, d] ----------------
#define EP 136   // Es pitch (halves): 272B rows, 16B-aligned, conflict-free frag reads
#define BP 40    // Bs pitch (halves): 80B rows

__global__ __launch_bounds__(256) void convA_kernel(
    const float* __restrict__ Gq, _Float16* __restrict__ H,
    const _Float16* __restrict__ eh) {
    __shared__ _Float16 Es[128 * EP];   // 34816 B (E, then reused as fp16 bounce)
    __shared__ _Float16 Bs[128 * BP];   // 10240 B
    const int dt = blockIdx.x;          // 0..2
    const int ib = blockIdx.y;          // 0..127
    const int d0 = dt * 128;
    const int tid = threadIdx.x;
    const int wv = tid >> 6, lane = tid & 63;
    const int l15 = lane & 15, q = lane >> 4;
    const int mrow = (wv >> 1) * 64, ncol = (wv & 1) * 64;

    {   // load E into LDS once
        const int row = tid >> 1, hh = tid & 1;
        const _Float16* src = eh + row * 128 + hh * 64;
        _Float16* dst = Es + row * EP + hh * 64;
        #pragma unroll
        for (int u = 0; u < 8; ++u) *(half8*)(dst + u * 8) = *(const half8*)(src + u * 8);
    }

    floatx4 acc[4][4];
    #pragma unroll
    for (int i = 0; i < 4; ++i)
        #pragma unroll
        for (int j = 0; j < 4; ++j) acc[i][j] = (floatx4){0.f, 0.f, 0.f, 0.f};

    const int jj2 = (tid & 15) * 2;     // k-row pair
    const int dd  = (tid >> 4) * 8;     // 8 d-cols per thread
    for (int k0 = 0; k0 < 128; k0 += 32) {
        __syncthreads();
        {   // stage Bs[d][j] fp16 (transpose + convert)
            const float* r0 = Gq + (size_t)(ib * 128 + k0 + jj2) * DH + d0 + dd;
            const float* r1 = r0 + DH;
            float4 a0 = *(const float4*)r0, a1 = *(const float4*)(r0 + 4);
            float4 b0 = *(const float4*)r1, b1 = *(const float4*)(r1 + 4);
            float va[8] = {a0.x, a0.y, a0.z, a0.w, a1.x, a1.y, a1.z, a1.w};
            float vb[8] = {b0.x, b0.y, b0.z, b0.w, b1.x, b1.y, b1.z, b1.w};
            #pragma unroll
            for (int u = 0; u < 8; ++u)
                *(half2v*)(Bs + (dd + u) * BP + jj2) = (half2v){(_Float16)va[u], (_Float16)vb[u]};
        }
        __syncthreads();
        half8 af[4], bf[4];
        #pragma unroll
        for (int i = 0; i < 4; ++i)
            af[i] = *(const half8*)(Es + (mrow + i * 16 + l15) * EP + k0 + q * 8);
        #pragma unroll
        for (int j = 0; j < 4; ++j)
            bf[j] = *(const half8*)(Bs + (ncol + j * 16 + l15) * BP + q * 8);
        #pragma unroll
        for (int i = 0; i < 4; ++i)
            #pragma unroll
            for (int j = 0; j < 4; ++j)
                acc[i][j] = __builtin_amdgcn_mfma_f32_16x16x32_f16(af[i], bf[j], acc[i][j], 0, 0, 0);
    }
    __syncthreads();
    // bounce acc -> Es (fp16) -> vectorized global store
    #pragma unroll
    for (int i = 0; i < 4; ++i)
        #pragma unroll
        for (int j = 0; j < 4; ++j)
            #pragma unroll
            for (int r = 0; r < 4; ++r)
                Es[(mrow + i * 16 + q * 4 + r) * EP + ncol + j * 16 + l15] = (_Float16)acc[i][j][r];
    __syncthreads();
    {
        const int row = tid >> 1, hh = tid & 1;
        const _Float16* src = Es + row * EP + hh * 64;
        _Float16* dst = H + ((size_t)ib * 128 + row) * DH + d0 + hh * 64;
        #pragma unroll
        for (int u = 0; u < 8; ++u) *(half8*)(dst + u * 8) = *(const half8*)(src + u * 8);
    }
}

// ---- conv pass B (MFMA) + fused epilogue: out = w*(1-alpha*S) + alpha * sum_i E[ic,i] H[i,jc,d] ----
__global__ __launch_bounds__(256) void convB_kernel(
    const _Float16* __restrict__ H, const float* __restrict__ w,
    const float* __restrict__ S, const _Float16* __restrict__ eh,
    const int* __restrict__ itp, float* __restrict__ out, int h) {
    __shared__ _Float16 Es[128 * EP];
    __shared__ _Float16 Bs[128 * BP];
    const int dt = blockIdx.x;          // 0..2
    const int jc = blockIdx.y;          // 0..127
    const int d0 = dt * 128;
    const int tid = threadIdx.x;
    const int wv = tid >> 6, lane = tid & 63;
    const int l15 = lane & 15, q = lane >> 4;
    const int mrow = (wv >> 1) * 64, ncol = (wv & 1) * 64;
    const float alpha = ALPHA0 * (1.f - (float)(*itp) / NITER_F);

    {
        const int row = tid >> 1, hh = tid & 1;
        const _Float16* src = eh + row * 128 + hh * 64;
        _Float16* dst = Es + row * EP + hh * 64;
        #pragma unroll
        for (int u = 0; u < 8; ++u) *(half8*)(dst + u * 8) = *(const half8*)(src + u * 8);
    }

    floatx4 acc[4][4];
    #pragma unroll
    for (int i = 0; i < 4; ++i)
        #pragma unroll
        for (int j = 0; j < 4; ++j) acc[i][j] = (floatx4){0.f, 0.f, 0.f, 0.f};

    const int jj2 = (tid & 15) * 2;
    const int dd  = (tid >> 4) * 8;
    for (int k0 = 0; k0 < 128; k0 += 32) {
        __syncthreads();
        {   // stage Bs[d][i] from H rows (stride 128*DH halves)
            const _Float16* r0 = H + ((size_t)(k0 + jj2) * 128 + jc) * DH + d0 + dd;
            const _Float16* r1 = r0 + (size_t)128 * DH;
            half8 a = *(const half8*)r0;
            half8 b = *(const half8*)r1;
            #pragma unroll
            for (int u = 0; u < 8; ++u)
                *(half2v*)(Bs + (dd + u) * BP + jj2) = (half2v){a[u], b[u]};
        }
        __syncthreads();
        half8 af[4], bf[4];
        #pragma unroll
        for (int i = 0; i < 4; ++i)
            af[i] = *(const half8*)(Es + (mrow + i * 16 + l15) * EP + k0 + q * 8);
        #pragma unroll
        for (int j = 0; j < 4; ++j)
            bf[j] = *(const half8*)(Bs + (ncol + j * 16 + l15) * BP + q * 8);
        #pragma unroll
        for (int i = 0; i < 4; ++i)
            #pragma unroll
            for (int j = 0; j < 4; ++j)
                acc[i][j] = __builtin_amdgcn_mfma_f32_16x16x32_f16(af[i], bf[j], acc[i][j], 0, 0, 0);
    }
    __syncthreads();
    // fused epilogue, fp32 bounce in 64-row chunks through Es region
    float* Ebf = (float*)Es;            // [64][132] floats = 33792 B <= 34816
    #pragma unroll
    for (int ch = 0; ch < 2; ++ch) {
        if ((wv >> 1) == ch) {
            #pragma unroll
            for (int i = 0; i < 4; ++i)
                #pragma unroll
                for (int j = 0; j < 4; ++j)
                    #pragma unroll
                    for (int r = 0; r < 4; ++r)
                        Ebf[(i * 16 + q * 4 + r) * 132 + ncol + j * 16 + l15] = acc[i][j][r];
        }
        __syncthreads();
        {
            const int row = tid >> 2, seg = tid & 3;    // 64 rows x 4 segs of 32 floats
            const int m = ch * 64 + row;
            const int c = m * 128 + jc;
            const float scl = 1.f - alpha * S[c];
            const size_t g = (size_t)c * DIM + h * DH + d0 + seg * 32;
            #pragma unroll
            for (int u = 0; u < 8; ++u) {
                float4 wv4 = *(const float4*)(w + g + u * 4);
                float4 t4  = *(const float4*)(Ebf + row * 132 + seg * 32 + u * 4);
                float4 o;
                o.x = wv4.x * scl + alpha * t4.x;
                o.y = wv4.y * scl + alpha * t4.y;
                o.z = wv4.z * scl + alpha * t4.z;
                o.w = wv4.w * scl + alpha * t4.w;
                *(float4*)(out + g + u * 4) = o;
            }
        }
        __syncthreads();
    }
}

// ---------------- count convolution (separable, fp32) ----------------
__global__ void cntconv1(const float* __restrict__ cnt, const float* __restrict__ etab,
                         float* __restrict__ cntH) {
    const int idx = blockIdx.x * 256 + threadIdx.x;  // i*128 + jc
    const int i = idx >> 7, jc = idx & 127;
    float s = 0.f;
    for (int j = 0; j < 128; ++j) s += etab[jc * 128 + j] * cnt[i * 128 + j];
    cntH[idx] = s;
}
__global__ void cntconv2(const float* __restrict__ cntH, const float* __restrict__ etab,
                         float* __restrict__ S) {
    const int idx = blockIdx.x * 256 + threadIdx.x;  // ic*128 + jc
    const int ic = idx >> 7, jc = idx & 127;
    float s = 0.f;
    for (int i = 0; i < 128; ++i) s += etab[ic * 128 + i] * cntH[i * 128 + jc];
    S[idx] = s;
}

extern "C" void kernel_launch(void* const* d_in, const int* in_sizes, int n_in,
                              void* d_out, int out_size, void* d_ws, size_t ws_size,
                              hipStream_t stream) {
    const float* x  = (const float*)d_in[0];   // [4096, 768]
    const float* w  = (const float*)d_in[1];   // [16384, 768]
    const int* itp  = (const int*)d_in[2];     // scalar it
    float* out = (float*)d_out;                // [16384, 768]
    char* ws = (char*)d_ws;

    _Float16* xh = (_Float16*)(ws + XH_OFF);
    _Float16* wh = (_Float16*)(ws + WH_OFF);
    float*    Gq = (float*)(ws + GQ_OFF);      // aliases xh/wh, used post-bmu
    _Float16* Hq = (_Float16*)(ws + HQ_OFF);   // aliases wh tail, used post-bmu
    _Float16* eh = (_Float16*)(ws + ETABH_OFF);
    unsigned long long* best = (unsigned long long*)(ws + BEST_OFF);
    float* cnt  = (float*)(ws + CNT_OFF);
    float* cntH = (float*)(ws + CNTH_OFF);
    float* S    = (float*)(ws + S_OFF);
    float* etab = (float*)(ws + ETAB_OFF);
    float* wn2  = (float*)(ws + WN2_OFF);

    hipMemsetAsync(ws + BEST_OFF, 0, BEST_BYTES + CNT_BYTES, stream);

    cvt_kernel<<<(BS * DIM / 4 + 255) / 256, 256, 0, stream>>>(x, xh, BS * DIM / 4);
    cvtw_wn2_kernel<<<COMPS, 192, 0, stream>>>(w, wh, wn2);
    etab_kernel<<<COMPS / 256, 256, 0, stream>>>(itp, etab, eh);

    bmu_kernel<<<dim3(COMPS / 128, BS / 128), 256, 0, stream>>>(xh, wh, wn2, best);

    for (int h = 0; h < 2; ++h) {
        hipMemsetAsync(ws + GQ_OFF, 0, GQ_BYTES, stream);
        scatter_kernel<<<BS, 128, 0, stream>>>(best, x, Gq, cnt, h, h == 0 ? 1 : 0);
        if (h == 0) {
            cntconv1<<<COMPS / 256, 256, 0, stream>>>(cnt, etab, cntH);
            cntconv2<<<COMPS / 256, 256, 0, stream>>>(cntH, etab, S);
        }
        convA_kernel<<<dim3(3, 128), 256, 0, stream>>>(Gq, Hq, eh);
        convB_kernel<<<dim3(3, 128), 256, 0, stream>>>(Hq, w, S, eh, itp, out, h);
    }
}

// Round 4
// 346.948 us; speedup vs baseline: 4.7776x; 1.0395x over previous
//
#include <hip/hip_runtime.h>
#include <cstdint>
#include <cstddef>

// ---------------- problem constants ----------------
#define BS    4096
#define DIM   768
#define GM    128
#define GN    128
#define COMPS (GM * GN)          // 16384
#define NITER_F 1000.0f
#define ALPHA0  0.3f
#define SIGMA0  64.0f            // max(M,N)/2

typedef _Float16 half8  __attribute__((ext_vector_type(8)));
typedef _Float16 half4v __attribute__((ext_vector_type(4)));
typedef _Float16 half2v __attribute__((ext_vector_type(2)));
typedef float    floatx4 __attribute__((ext_vector_type(4)));

// ---------------- workspace layout (bytes) ----------------
// Phase 1 (pre-bmu): xh fp16 @0 (6.3MB), wh fp16 @8MB (25.2MB).
// Phase 2 (post-bmu): G fp32 full-width @0 (50.33MB) — aliases xh/wh (dead).
// H lives in d_out (convA writes it, convB consumes it in-place).
// Tails at >=50.33MB: best, cnt, cntH, S, wn2  (ends 50,625,536 < proven ws).
#define XH_OFF    0UL
#define WH_OFF    (8UL * 1024UL * 1024UL)
#define G_OFF     0UL
#define G_BYTES   ((size_t)COMPS * DIM * 4UL)     // 50,331,648
#define BEST_OFF  G_BYTES
#define BEST_BYTES ((size_t)BS * 8UL)             // 32 KB
#define CNT_OFF   (BEST_OFF + BEST_BYTES)
#define CNT_BYTES ((size_t)COMPS * 4UL)           // 64 KB
#define CNTH_OFF  (CNT_OFF + CNT_BYTES)
#define S_OFF     (CNTH_OFF + CNT_BYTES)
#define WN2_OFF   (S_OFF + CNT_BYTES)

#define GPTR(p) ((const __attribute__((address_space(1))) void*)(p))
#define LPTR(p) ((__attribute__((address_space(3))) void*)(p))

// pack (score, index) so that u64 max == (max score, min index on ties)
__device__ __forceinline__ unsigned long long packScore(float s, int c) {
    unsigned u = __float_as_uint(s);
    u = (u & 0x80000000u) ? ~u : (u | 0x80000000u);   // order-preserving map
    return ((unsigned long long)u << 32) | (unsigned)(~(unsigned)c);
}

__device__ __forceinline__ unsigned long long shfl_xor_u64(unsigned long long v, int m) {
    unsigned lo = (unsigned)v, hi = (unsigned)(v >> 32);
    lo = (unsigned)__shfl_xor((int)lo, m, 64);
    hi = (unsigned)__shfl_xor((int)hi, m, 64);
    return ((unsigned long long)hi << 32) | lo;
}

// ---------------- fp32 -> fp16 convert (x) ----------------
__global__ void cvt_kernel(const float* __restrict__ src, _Float16* __restrict__ dst, int n4) {
    int i = blockIdx.x * 256 + threadIdx.x;
    if (i >= n4) return;
    float4 v = ((const float4*)src)[i];
    half4v h;
    h[0] = (_Float16)v.x; h[1] = (_Float16)v.y;
    h[2] = (_Float16)v.z; h[3] = (_Float16)v.w;
    ((half4v*)dst)[i] = h;
}

// ---------------- w: fp32->fp16 convert fused with 0.5*||w_c||^2 ----------------
__global__ __launch_bounds__(192) void cvtw_wn2_kernel(
    const float* __restrict__ w, _Float16* __restrict__ wh, float* __restrict__ wn2) {
    const int c = blockIdx.x;
    const int t = threadIdx.x;                   // 0..191 (one float4 each)
    const size_t i4 = (size_t)c * 192 + t;
    float4 v = ((const float4*)w)[i4];
    half4v h;
    h[0] = (_Float16)v.x; h[1] = (_Float16)v.y;
    h[2] = (_Float16)v.z; h[3] = (_Float16)v.w;
    ((half4v*)wh)[i4] = h;
    float s = v.x * v.x + v.y * v.y + v.z * v.z + v.w * v.w;
    #pragma unroll
    for (int off = 32; off; off >>= 1) s += __shfl_down(s, off, 64);
    __shared__ float p[3];
    if ((t & 63) == 0) p[t >> 6] = s;
    __syncthreads();
    if (t == 0) wn2[c] = 0.5f * (p[0] + p[1] + p[2]);
}

// ---------------- MFMA BMU: best_b = argmax_c (x_b.w_c - 0.5||w_c||^2) ----------------
// 128x128 tile, BK=32, v_mfma_f32_16x16x32_f16, XOR-swizzled LDS quads.
__global__ __launch_bounds__(256) void bmu_kernel(
    const _Float16* __restrict__ xh, const _Float16* __restrict__ wh,
    const float* __restrict__ wn2, unsigned long long* __restrict__ best) {
    __shared__ _Float16 xs[128 * 32];    // [row][quad-swizzled k], 64B rows
    __shared__ _Float16 wsd[128 * 32];
    __shared__ unsigned long long red[128];

    const int tid  = threadIdx.x;
    const int wv   = tid >> 6;
    const int lane = tid & 63;
    const int c0 = blockIdx.x * 128;
    const int b0 = blockIdx.y * 128;

    if (tid < 128) red[tid] = 0ULL;

    floatx4 acc[4][4];
    #pragma unroll
    for (int i = 0; i < 4; ++i)
        #pragma unroll
        for (int j = 0; j < 4; ++j) acc[i][j] = (floatx4){0.f, 0.f, 0.f, 0.f};

    const int rr   = lane >> 2;              // staging row within 16-row sub-chunk
    const int pq   = lane & 3;               // LDS quad position (fixed by HW lane map)
    const int kk   = pq ^ ((rr >> 1) & 3);   // swizzled global k-chunk
    const int lk   = kk * 8;
    const int q    = lane >> 4;              // MFMA k-quad
    const int l15  = lane & 15;
    const int mrow = (wv >> 1) * 64;
    const int ncol = (wv & 1) * 64;

    for (int k0 = 0; k0 < DIM; k0 += 32) {
        #pragma unroll
        for (int s = 0; s < 2; ++s) {
            const int sub = 2 * wv + s;                  // 0..7
            const _Float16* gx = xh + (size_t)(b0 + sub * 16 + rr) * DIM + k0 + lk;
            __builtin_amdgcn_global_load_lds(GPTR(gx), LPTR(xs + sub * 512), 16, 0, 0);
            const _Float16* gw = wh + (size_t)(c0 + sub * 16 + rr) * DIM + k0 + lk;
            __builtin_amdgcn_global_load_lds(GPTR(gw), LPTR(wsd + sub * 512), 16, 0, 0);
        }
        __syncthreads();

        half8 af[4], bf[4];
        #pragma unroll
        for (int i = 0; i < 4; ++i) {
            const int row = mrow + i * 16 + l15;
            af[i] = *(const half8*)(xs + row * 32 + (q ^ ((row >> 1) & 3)) * 8);
        }
        #pragma unroll
        for (int j = 0; j < 4; ++j) {
            const int row = ncol + j * 16 + l15;
            bf[j] = *(const half8*)(wsd + row * 32 + (q ^ ((row >> 1) & 3)) * 8);
        }
        #pragma unroll
        for (int i = 0; i < 4; ++i)
            #pragma unroll
            for (int j = 0; j < 4; ++j)
                acc[i][j] = __builtin_amdgcn_mfma_f32_16x16x32_f16(af[i], bf[j], acc[i][j], 0, 0, 0);
        __syncthreads();
    }

    float wnj[4];
    #pragma unroll
    for (int j = 0; j < 4; ++j) wnj[j] = wn2[c0 + ncol + j * 16 + l15];

    #pragma unroll
    for (int i = 0; i < 4; ++i) {
        #pragma unroll
        for (int r = 0; r < 4; ++r) {
            unsigned long long m = 0ULL;
            #pragma unroll
            for (int j = 0; j < 4; ++j) {
                float s = acc[i][j][r] - wnj[j];
                unsigned long long p = packScore(s, c0 + ncol + j * 16 + l15);
                if (p > m) m = p;
            }
            #pragma unroll
            for (int msk = 1; msk <= 8; msk <<= 1) {
                unsigned long long o = shfl_xor_u64(m, msk);
                if (o > m) m = o;
            }
            if (l15 == 0)
                atomicMax(&red[mrow + i * 16 + q * 4 + r], m);
        }
    }
    __syncthreads();
    if (tid < 128) atomicMax(&best[b0 + tid], red[tid]);
}

// ---------------- scatter x rows into full-width G + histogram ----------------
__global__ void scatter_kernel(const unsigned long long* __restrict__ best,
                               const float* __restrict__ x,
                               float* __restrict__ G, float* __restrict__ cnt) {
    const int b = blockIdx.x;
    const int c = (int)(~(unsigned)(best[b] & 0xFFFFFFFFULL));
    float* gr = G + (size_t)c * DIM;
    const float* xr = x + (size_t)b * DIM;
    #pragma unroll
    for (int u = 0; u < 3; ++u) {
        const int d = threadIdx.x + u * 256;
        atomicAdd(&gr[d], xr[d]);
    }
    if (threadIdx.x == 0) atomicAdd(&cnt[c], 1.0f);
}

#define EP 136   // Es pitch (halves): 272B rows => 16B/lane stagger, 2-way (free)
#define BP 40    // Bs pitch (halves): 80B rows

// ---------------- conv pass A (MFMA): H[(i,jc), d] = sum_j E[jc,j] * G[(i,j), d] ----------------
__global__ __launch_bounds__(256) void convA_kernel(
    const float* __restrict__ G, float* __restrict__ H, const int* __restrict__ itp) {
    __shared__ _Float16 Es[128 * EP];   // E fp16, later reused as fp32 bounce
    __shared__ _Float16 Bs[128 * BP];
    const int d0 = blockIdx.x * 128;    // 0..5
    const int ib = blockIdx.y;          // 0..127
    const int tid = threadIdx.x;
    const int wv = tid >> 6, lane = tid & 63;
    const int l15 = lane & 15, q = lane >> 4;
    const int mrow = (wv >> 1) * 64, ncol = (wv & 1) * 64;

    {   // compute E tile in LDS on the fly
        const float decay = 1.f - (float)(*itp) / NITER_F;
        const float sig = SIGMA0 * decay;
        const float inv = -1.f / (sig * sig);
        const int row = tid >> 1, hh = tid & 1;
        _Float16* dst = Es + row * EP + hh * 64;
        #pragma unroll
        for (int u = 0; u < 64; ++u) {
            const float dd = (float)(row - hh * 64 - u);
            dst[u] = (_Float16)__expf(dd * dd * inv);
        }
    }

    floatx4 acc[4][4];
    #pragma unroll
    for (int i = 0; i < 4; ++i)
        #pragma unroll
        for (int j = 0; j < 4; ++j) acc[i][j] = (floatx4){0.f, 0.f, 0.f, 0.f};

    const int jj2 = (tid & 15) * 2;     // k-row pair
    const int dd  = (tid >> 4) * 8;     // 8 d-cols per thread
    for (int k0 = 0; k0 < 128; k0 += 32) {
        __syncthreads();
        {   // stage Bs[d][j] fp16 (transpose + convert from fp32 G)
            const float* r0 = G + (size_t)(ib * 128 + k0 + jj2) * DIM + d0 + dd;
            const float* r1 = r0 + DIM;
            float4 a0 = *(const float4*)r0, a1 = *(const float4*)(r0 + 4);
            float4 b0 = *(const float4*)r1, b1 = *(const float4*)(r1 + 4);
            float va[8] = {a0.x, a0.y, a0.z, a0.w, a1.x, a1.y, a1.z, a1.w};
            float vb[8] = {b0.x, b0.y, b0.z, b0.w, b1.x, b1.y, b1.z, b1.w};
            #pragma unroll
            for (int u = 0; u < 8; ++u)
                *(half2v*)(Bs + (dd + u) * BP + jj2) = (half2v){(_Float16)va[u], (_Float16)vb[u]};
        }
        __syncthreads();
        half8 af[4], bf[4];
        #pragma unroll
        for (int i = 0; i < 4; ++i)
            af[i] = *(const half8*)(Es + (mrow + i * 16 + l15) * EP + k0 + q * 8);
        #pragma unroll
        for (int j = 0; j < 4; ++j)
            bf[j] = *(const half8*)(Bs + (ncol + j * 16 + l15) * BP + q * 8);
        #pragma unroll
        for (int i = 0; i < 4; ++i)
            #pragma unroll
            for (int j = 0; j < 4; ++j)
                acc[i][j] = __builtin_amdgcn_mfma_f32_16x16x32_f16(af[i], bf[j], acc[i][j], 0, 0, 0);
    }
    __syncthreads();
    // fp32 bounce epilogue in 2 chunks of 64 rows (m = jc)
    float* Ebf = (float*)Es;            // [64][132] floats = 33792 B <= 34816
    #pragma unroll
    for (int ch = 0; ch < 2; ++ch) {
        if ((wv >> 1) == ch) {
            #pragma unroll
            for (int i = 0; i < 4; ++i)
                #pragma unroll
                for (int j = 0; j < 4; ++j)
                    #pragma unroll
                    for (int r = 0; r < 4; ++r)
                        Ebf[(i * 16 + q * 4 + r) * 132 + ncol + j * 16 + l15] = acc[i][j][r];
        }
        __syncthreads();
        {
            const int row = tid >> 2, seg = tid & 3;    // 64 rows x 4 segs of 32 floats
            const int m = ch * 64 + row;
            const size_t g = (size_t)(ib * 128 + m) * DIM + d0 + seg * 32;
            #pragma unroll
            for (int u = 0; u < 8; ++u)
                *(float4*)(H + g + u * 4) = *(const float4*)(Ebf + row * 132 + seg * 32 + u * 4);
        }
        __syncthreads();
    }
}

// ---- conv pass B (MFMA), H in-place in out: out[(ic,jc),d] = w*(1-a*S) + a*sum_i E[ic,i]H[(i,jc),d]
// NOTE: H and out alias (both = d_out). Safe: all reads complete before the
// post-k-loop barrier; blocks with same jc have disjoint d-ranges; different jc
// touch disjoint rows. No __restrict__ on H/out.
__global__ __launch_bounds__(256) void convB_kernel(
    const float* H, const float* __restrict__ w,
    const float* __restrict__ S, const int* __restrict__ itp, float* out) {
    __shared__ _Float16 Es[128 * EP];
    __shared__ _Float16 Bs[128 * BP];
    const int d0 = blockIdx.x * 128;    // 0..5
    const int jc = blockIdx.y;          // 0..127
    const int tid = threadIdx.x;
    const int wv = tid >> 6, lane = tid & 63;
    const int l15 = lane & 15, q = lane >> 4;
    const int mrow = (wv >> 1) * 64, ncol = (wv & 1) * 64;
    const float alpha = ALPHA0 * (1.f - (float)(*itp) / NITER_F);

    {   // compute E tile in LDS on the fly
        const float decay = 1.f - (float)(*itp) / NITER_F;
        const float sig = SIGMA0 * decay;
        const float inv = -1.f / (sig * sig);
        const int row = tid >> 1, hh = tid & 1;
        _Float16* dst = Es + row * EP + hh * 64;
        #pragma unroll
        for (int u = 0; u < 64; ++u) {
            const float dd = (float)(row - hh * 64 - u);
            dst[u] = (_Float16)__expf(dd * dd * inv);
        }
    }

    floatx4 acc[4][4];
    #pragma unroll
    for (int i = 0; i < 4; ++i)
        #pragma unroll
        for (int j = 0; j < 4; ++j) acc[i][j] = (floatx4){0.f, 0.f, 0.f, 0.f};

    const int jj2 = (tid & 15) * 2;
    const int dd  = (tid >> 4) * 8;
    for (int k0 = 0; k0 < 128; k0 += 32) {
        __syncthreads();
        {   // stage Bs[d][i] from H rows (i,jc) = row index i*128+jc
            const float* r0 = H + (size_t)((k0 + jj2) * 128 + jc) * DIM + d0 + dd;
            const float* r1 = r0 + (size_t)128 * DIM;
            float4 a0 = *(const float4*)r0, a1 = *(const float4*)(r0 + 4);
            float4 b0 = *(const float4*)r1, b1 = *(const float4*)(r1 + 4);
            float va[8] = {a0.x, a0.y, a0.z, a0.w, a1.x, a1.y, a1.z, a1.w};
            float vb[8] = {b0.x, b0.y, b0.z, b0.w, b1.x, b1.y, b1.z, b1.w};
            #pragma unroll
            for (int u = 0; u < 8; ++u)
                *(half2v*)(Bs + (dd + u) * BP + jj2) = (half2v){(_Float16)va[u], (_Float16)vb[u]};
        }
        __syncthreads();
        half8 af[4], bf[4];
        #pragma unroll
        for (int i = 0; i < 4; ++i)
            af[i] = *(const half8*)(Es + (mrow + i * 16 + l15) * EP + k0 + q * 8);
        #pragma unroll
        for (int j = 0; j < 4; ++j)
            bf[j] = *(const half8*)(Bs + (ncol + j * 16 + l15) * BP + q * 8);
        #pragma unroll
        for (int i = 0; i < 4; ++i)
            #pragma unroll
            for (int j = 0; j < 4; ++j)
                acc[i][j] = __builtin_amdgcn_mfma_f32_16x16x32_f16(af[i], bf[j], acc[i][j], 0, 0, 0);
    }
    __syncthreads();
    // fused epilogue: fp32 bounce in 2 chunks of 64 rows (m = ic)
    float* Ebf = (float*)Es;            // [64][132] floats
    #pragma unroll
    for (int ch = 0; ch < 2; ++ch) {
        if ((wv >> 1) == ch) {
            #pragma unroll
            for (int i = 0; i < 4; ++i)
                #pragma unroll
                for (int j = 0; j < 4; ++j)
                    #pragma unroll
                    for (int r = 0; r < 4; ++r)
                        Ebf[(i * 16 + q * 4 + r) * 132 + ncol + j * 16 + l15] = acc[i][j][r];
        }
        __syncthreads();
        {
            const int row = tid >> 2, seg = tid & 3;    // 64 rows x 4 segs of 32 floats
            const int m = ch * 64 + row;                // ic
            const int c = m * 128 + jc;
            const float scl = 1.f - alpha * S[c];
            const size_t g = (size_t)c * DIM + d0 + seg * 32;
            #pragma unroll
            for (int u = 0; u < 8; ++u) {
                float4 wv4 = *(const float4*)(w + g + u * 4);
                float4 t4  = *(const float4*)(Ebf + row * 132 + seg * 32 + u * 4);
                float4 o;
                o.x = wv4.x * scl + alpha * t4.x;
                o.y = wv4.y * scl + alpha * t4.y;
                o.z = wv4.z * scl + alpha * t4.z;
                o.w = wv4.w * scl + alpha * t4.w;
                *(float4*)(out + g + u * 4) = o;
            }
        }
        __syncthreads();
    }
}

// ---------------- count convolution (separable, fp32, E on-the-fly) ----------------
__global__ void cntconv1(const float* __restrict__ cnt, float* __restrict__ cntH,
                         const int* __restrict__ itp) {
    const int idx = blockIdx.x * 256 + threadIdx.x;  // i*128 + jc
    const int i = idx >> 7, jc = idx & 127;
    const float decay = 1.f - (float)(*itp) / NITER_F;
    const float sig = SIGMA0 * decay;
    const float inv = -1.f / (sig * sig);
    float s = 0.f;
    for (int j = 0; j < 128; ++j) {
        const float dd = (float)(jc - j);
        s += __expf(dd * dd * inv) * cnt[i * 128 + j];
    }
    cntH[idx] = s;
}
__global__ void cntconv2(const float* __restrict__ cntH, float* __restrict__ S,
                         const int* __restrict__ itp) {
    const int idx = blockIdx.x * 256 + threadIdx.x;  // ic*128 + jc
    const int ic = idx >> 7, jc = idx & 127;
    const float decay = 1.f - (float)(*itp) / NITER_F;
    const float sig = SIGMA0 * decay;
    const float inv = -1.f / (sig * sig);
    float s = 0.f;
    for (int i = 0; i < 128; ++i) {
        const float dd = (float)(ic - i);
        s += __expf(dd * dd * inv) * cntH[i * 128 + jc];
    }
    S[idx] = s;
}

extern "C" void kernel_launch(void* const* d_in, const int* in_sizes, int n_in,
                              void* d_out, int out_size, void* d_ws, size_t ws_size,
                              hipStream_t stream) {
    const float* x  = (const float*)d_in[0];   // [4096, 768]
    const float* w  = (const float*)d_in[1];   // [16384, 768]
    const int* itp  = (const int*)d_in[2];     // scalar it
    float* out = (float*)d_out;                // [16384, 768]
    char* ws = (char*)d_ws;

    _Float16* xh = (_Float16*)(ws + XH_OFF);
    _Float16* wh = (_Float16*)(ws + WH_OFF);
    float*    G  = (float*)(ws + G_OFF);       // aliases xh/wh, used post-bmu
    unsigned long long* best = (unsigned long long*)(ws + BEST_OFF);
    float* cnt  = (float*)(ws + CNT_OFF);
    float* cntH = (float*)(ws + CNTH_OFF);
    float* S    = (float*)(ws + S_OFF);
    float* wn2  = (float*)(ws + WN2_OFF);

    hipMemsetAsync(ws + BEST_OFF, 0, BEST_BYTES + CNT_BYTES, stream);

    cvt_kernel<<<(BS * DIM / 4 + 255) / 256, 256, 0, stream>>>(x, xh, BS * DIM / 4);
    cvtw_wn2_kernel<<<COMPS, 192, 0, stream>>>(w, wh, wn2);

    bmu_kernel<<<dim3(COMPS / 128, BS / 128), 256, 0, stream>>>(xh, wh, wn2, best);

    // xh/wh dead -> zero full G (stream-ordered after bmu)
    hipMemsetAsync(ws + G_OFF, 0, G_BYTES, stream);
    scatter_kernel<<<BS, 256, 0, stream>>>(best, x, G, cnt);

    cntconv1<<<COMPS / 256, 256, 0, stream>>>(cnt, cntH, itp);
    cntconv2<<<COMPS / 256, 256, 0, stream>>>(cntH, S, itp);

    // pass A: H[(i,jc),d] = sum_j E[jc,j] G[(i,j),d]   (G -> d_out)
    convA_kernel<<<dim3(6, 128), 256, 0, stream>>>(G, out, itp);
    // pass B (in-place on d_out) + fused epilogue
    convB_kernel<<<dim3(6, 128), 256, 0, stream>>>(out, w, S, itp, out);
}

// Round 5
// 345.229 us; speedup vs baseline: 4.8014x; 1.0050x over previous
//
#include <hip/hip_runtime.h>
#include <cstdint>
#include <cstddef>

// ---------------- problem constants ----------------
#define BS    4096
#define DIM   768
#define GM    128
#define GN    128
#define COMPS (GM * GN)          // 16384
#define NITER_F 1000.0f
#define ALPHA0  0.3f
#define SIGMA0  64.0f            // max(M,N)/2

typedef _Float16 half8  __attribute__((ext_vector_type(8)));
typedef _Float16 half4v __attribute__((ext_vector_type(4)));
typedef float    floatx4 __attribute__((ext_vector_type(4)));

// ---------------- workspace layout (bytes) ----------------
// Phase 1 (pre-bmu): xh fp16 @0 (6.3MB), wh fp16 @8MB (25.2MB).
// Phase 2 (post-bmu): G fp32 full-width @0 (50.33MB) — aliases xh/wh (dead).
// H fp16 lives packed INSIDE G's rows: chunk (c, d0) at bytes
//   c*3072 + d0*4 + 2*(d-d0)  — convA block (ib,d0) writes only words
//   [d0, d0+64) of rows it alone reads at [d0, d0+128): race-free.
// Tails at >=50.33MB: best, cnt, wn2.
#define XH_OFF    0UL
#define WH_OFF    (8UL * 1024UL * 1024UL)
#define G_OFF     0UL
#define G_BYTES   ((size_t)COMPS * DIM * 4UL)     // 50,331,648
#define BEST_OFF  G_BYTES
#define BEST_BYTES ((size_t)BS * 8UL)             // 32 KB
#define CNT_OFF   (BEST_OFF + BEST_BYTES)
#define CNT_BYTES ((size_t)COMPS * 4UL)           // 64 KB
#define WN2_OFF   (CNT_OFF + CNT_BYTES)

#define GPTR(p) ((const __attribute__((address_space(1))) void*)(p))
#define LPTR(p) ((__attribute__((address_space(3))) void*)(p))

// pack (score, index) so that u64 max == (max score, min index on ties)
__device__ __forceinline__ unsigned long long packScore(float s, int c) {
    unsigned u = __float_as_uint(s);
    u = (u & 0x80000000u) ? ~u : (u | 0x80000000u);   // order-preserving map
    return ((unsigned long long)u << 32) | (unsigned)(~(unsigned)c);
}

__device__ __forceinline__ unsigned long long shfl_xor_u64(unsigned long long v, int m) {
    unsigned lo = (unsigned)v, hi = (unsigned)(v >> 32);
    lo = (unsigned)__shfl_xor((int)lo, m, 64);
    hi = (unsigned)__shfl_xor((int)hi, m, 64);
    return ((unsigned long long)hi << 32) | lo;
}

// ---------------- fp32 -> fp16 convert (x) ----------------
__global__ void cvt_kernel(const float* __restrict__ src, _Float16* __restrict__ dst, int n4) {
    int i = blockIdx.x * 256 + threadIdx.x;
    if (i >= n4) return;
    float4 v = ((const float4*)src)[i];
    half4v h;
    h[0] = (_Float16)v.x; h[1] = (_Float16)v.y;
    h[2] = (_Float16)v.z; h[3] = (_Float16)v.w;
    ((half4v*)dst)[i] = h;
}

// ---------------- w: fp32->fp16 convert fused with 0.5*||w_c||^2 ----------------
__global__ __launch_bounds__(192) void cvtw_wn2_kernel(
    const float* __restrict__ w, _Float16* __restrict__ wh, float* __restrict__ wn2) {
    const int c = blockIdx.x;
    const int t = threadIdx.x;                   // 0..191 (one float4 each)
    const size_t i4 = (size_t)c * 192 + t;
    float4 v = ((const float4*)w)[i4];
    half4v h;
    h[0] = (_Float16)v.x; h[1] = (_Float16)v.y;
    h[2] = (_Float16)v.z; h[3] = (_Float16)v.w;
    ((half4v*)wh)[i4] = h;
    float s = v.x * v.x + v.y * v.y + v.z * v.z + v.w * v.w;
    #pragma unroll
    for (int off = 32; off; off >>= 1) s += __shfl_down(s, off, 64);
    __shared__ float p[3];
    if ((t & 63) == 0) p[t >> 6] = s;
    __syncthreads();
    if (t == 0) wn2[c] = 0.5f * (p[0] + p[1] + p[2]);
}

// ---------------- MFMA BMU: best_b = argmax_c (x_b.w_c - 0.5||w_c||^2) ----------------
// 128x128 tile, BK=64, v_mfma_f32_16x16x32_f16, 8-position XOR-swizzled chunks.
__global__ __launch_bounds__(256) void bmu_kernel(
    const _Float16* __restrict__ xh, const _Float16* __restrict__ wh,
    const float* __restrict__ wn2, unsigned long long* __restrict__ best) {
    __shared__ _Float16 xs[128 * 64];    // [row][swizzled 8-half chunks], 128B rows
    __shared__ _Float16 wsd[128 * 64];
    __shared__ unsigned long long red[128];

    const int tid  = threadIdx.x;
    const int wv   = tid >> 6;
    const int lane = tid & 63;
    const int c0 = blockIdx.x * 128;
    const int b0 = blockIdx.y * 128;

    if (tid < 128) red[tid] = 0ULL;

    floatx4 acc[4][4];
    #pragma unroll
    for (int i = 0; i < 4; ++i)
        #pragma unroll
        for (int j = 0; j < 4; ++j) acc[i][j] = (floatx4){0.f, 0.f, 0.f, 0.f};

    const int srow = lane >> 3;          // 0..7: row within 8-row staging sub-block
    const int spos = lane & 7;           // chunk position in LDS row
    const int q    = lane >> 4;          // MFMA k-quad
    const int l15  = lane & 15;
    const int mrow = (wv >> 1) * 64;
    const int ncol = (wv & 1) * 64;

    for (int k0 = 0; k0 < DIM; k0 += 64) {
        #pragma unroll
        for (int s = 0; s < 4; ++s) {
            const int rbase = wv * 32 + s * 8;           // wave-uniform
            const int row = rbase + srow;
            const int kk = spos ^ (row & 7);             // swizzled source chunk
            const _Float16* gx = xh + (size_t)(b0 + row) * DIM + k0 + kk * 8;
            __builtin_amdgcn_global_load_lds(GPTR(gx), LPTR(xs + rbase * 64), 16, 0, 0);
            const _Float16* gw = wh + (size_t)(c0 + row) * DIM + k0 + kk * 8;
            __builtin_amdgcn_global_load_lds(GPTR(gw), LPTR(wsd + rbase * 64), 16, 0, 0);
        }
        __syncthreads();

        #pragma unroll
        for (int h = 0; h < 2; ++h) {
            half8 af[4], bf[4];
            #pragma unroll
            for (int i = 0; i < 4; ++i) {
                const int row = mrow + i * 16 + l15;
                const int ck = (h * 4 + q) ^ (row & 7);
                af[i] = *(const half8*)(xs + row * 64 + ck * 8);
            }
            #pragma unroll
            for (int j = 0; j < 4; ++j) {
                const int row = ncol + j * 16 + l15;
                const int ck = (h * 4 + q) ^ (row & 7);
                bf[j] = *(const half8*)(wsd + row * 64 + ck * 8);
            }
            #pragma unroll
            for (int i = 0; i < 4; ++i)
                #pragma unroll
                for (int j = 0; j < 4; ++j)
                    acc[i][j] = __builtin_amdgcn_mfma_f32_16x16x32_f16(af[i], bf[j], acc[i][j], 0, 0, 0);
        }
        __syncthreads();
    }

    float wnj[4];
    #pragma unroll
    for (int j = 0; j < 4; ++j) wnj[j] = wn2[c0 + ncol + j * 16 + l15];

    #pragma unroll
    for (int i = 0; i < 4; ++i) {
        #pragma unroll
        for (int r = 0; r < 4; ++r) {
            unsigned long long m = 0ULL;
            #pragma unroll
            for (int j = 0; j < 4; ++j) {
                float s = acc[i][j][r] - wnj[j];
                unsigned long long p = packScore(s, c0 + ncol + j * 16 + l15);
                if (p > m) m = p;
            }
            #pragma unroll
            for (int msk = 1; msk <= 8; msk <<= 1) {
                unsigned long long o = shfl_xor_u64(m, msk);
                if (o > m) m = o;
            }
            if (l15 == 0)
                atomicMax(&red[mrow + i * 16 + q * 4 + r], m);
        }
    }
    __syncthreads();
    if (tid < 128) atomicMax(&best[b0 + tid], red[tid]);
}

// ---------------- scatter x rows into full-width G + histogram ----------------
__global__ void scatter_kernel(const unsigned long long* __restrict__ best,
                               const float* __restrict__ x,
                               float* __restrict__ G, float* __restrict__ cnt) {
    const int b = blockIdx.x;
    const int c = (int)(~(unsigned)(best[b] & 0xFFFFFFFFULL));
    float* gr = G + (size_t)c * DIM;
    const float* xr = x + (size_t)b * DIM;
    #pragma unroll
    for (int u = 0; u < 3; ++u) {
        const int d = threadIdx.x + u * 256;
        atomicAdd(&gr[d], xr[d]);
    }
    if (threadIdx.x == 0) atomicAdd(&cnt[c], 1.0f);
}

#define EP 136   // Es pitch (halves)
#define BP 40    // Bs pitch (halves)

// ---- conv pass A (MFMA): H[(i,jc), d] = sum_j E[jc,j] * G[(i,j), d]; H fp16 packed into G rows ----
__global__ __launch_bounds__(256) void convA_kernel(
    const float* G, _Float16* Hh, const int* __restrict__ itp) {
    __shared__ _Float16 Es[128 * EP];   // E fp16, later reused as fp32 bounce
    __shared__ _Float16 Bs[128 * BP];
    const int d0 = blockIdx.x * 128;    // 0..5
    const int ib = blockIdx.y;          // 0..127
    const int tid = threadIdx.x;
    const int wv = tid >> 6, lane = tid & 63;
    const int l15 = lane & 15, q = lane >> 4;
    const int mrow = (wv >> 1) * 64, ncol = (wv & 1) * 64;

    {   // compute E tile in LDS on the fly
        const float decay = 1.f - (float)(*itp) / NITER_F;
        const float sig = SIGMA0 * decay;
        const float inv = -1.f / (sig * sig);
        const int row = tid >> 1, hh = tid & 1;
        _Float16* dst = Es + row * EP + hh * 64;
        #pragma unroll
        for (int u = 0; u < 64; ++u) {
            const float dd = (float)(row - hh * 64 - u);
            dst[u] = (_Float16)__expf(dd * dd * inv);
        }
    }

    floatx4 acc[4][4];
    #pragma unroll
    for (int i = 0; i < 4; ++i)
        #pragma unroll
        for (int j = 0; j < 4; ++j) acc[i][j] = (floatx4){0.f, 0.f, 0.f, 0.f};

    const int dpo = (tid & 15) * 8;     // d-octet within 128
    const int rsel = tid >> 4;          // 0..15 row selector
    for (int k0 = 0; k0 < 128; k0 += 32) {
        __syncthreads();
        #pragma unroll
        for (int s = 0; s < 2; ++s) {   // coalesced: 16 lanes read one row's 512B
            const int j = k0 + s * 16 + rsel;
            const float* r = G + (size_t)(ib * 128 + j) * DIM + d0 + dpo;
            float4 a0 = *(const float4*)r, a1 = *(const float4*)(r + 4);
            float va[8] = {a0.x, a0.y, a0.z, a0.w, a1.x, a1.y, a1.z, a1.w};
            #pragma unroll
            for (int u = 0; u < 8; ++u)
                Bs[(dpo + u) * BP + (s * 16 + rsel)] = (_Float16)va[u];
        }
        __syncthreads();
        half8 af[4], bf[4];
        #pragma unroll
        for (int i = 0; i < 4; ++i)
            af[i] = *(const half8*)(Es + (mrow + i * 16 + l15) * EP + k0 + q * 8);
        #pragma unroll
        for (int j = 0; j < 4; ++j)
            bf[j] = *(const half8*)(Bs + (ncol + j * 16 + l15) * BP + q * 8);
        #pragma unroll
        for (int i = 0; i < 4; ++i)
            #pragma unroll
            for (int j = 0; j < 4; ++j)
                acc[i][j] = __builtin_amdgcn_mfma_f32_16x16x32_f16(af[i], bf[j], acc[i][j], 0, 0, 0);
    }
    __syncthreads();
    // fp32 bounce epilogue in 2 chunks of 64 rows (m = jc), write H fp16 chunk-packed
    float* Ebf = (float*)Es;            // [64][132] floats = 33792 B <= 34816
    #pragma unroll
    for (int ch = 0; ch < 2; ++ch) {
        if ((wv >> 1) == ch) {
            #pragma unroll
            for (int i = 0; i < 4; ++i)
                #pragma unroll
                for (int j = 0; j < 4; ++j)
                    #pragma unroll
                    for (int r = 0; r < 4; ++r)
                        Ebf[(i * 16 + q * 4 + r) * 132 + ncol + j * 16 + l15] = acc[i][j][r];
        }
        __syncthreads();
        {
            const int row = tid >> 2, seg = tid & 3;    // 64 rows x 4 segs of 32
            const int m = ch * 64 + row;                // jc
            // H chunk-packed: half-index = c*1536 + d0*2 + dl
            _Float16* hp = Hh + (size_t)(ib * 128 + m) * 1536 + d0 * 2 + seg * 32;
            #pragma unroll
            for (int u = 0; u < 4; ++u) {
                const float* sp = Ebf + row * 132 + seg * 32 + u * 8;
                half8 hv;
                #pragma unroll
                for (int e = 0; e < 8; ++e) hv[e] = (_Float16)sp[e];
                *(half8*)(hp + u * 8) = hv;
            }
        }
        __syncthreads();
    }
}

// ---- conv pass B (MFMA) + fused S-conv + epilogue:
//      out[(ic,jc),d] = w*(1-a*S[ic,jc]) + a * sum_i E[ic,i] H[(i,jc),d]
__global__ __launch_bounds__(256) void convB_kernel(
    const _Float16* Hh, const float* __restrict__ w, const float* __restrict__ cnt,
    const int* __restrict__ itp, float* __restrict__ out) {
    __shared__ _Float16 Es[128 * EP];
    __shared__ _Float16 Bs[128 * BP];
    __shared__ float cntHs[128];
    __shared__ float Ss[128];
    const int d0 = blockIdx.x * 128;    // 0..5
    const int jc = blockIdx.y;          // 0..127
    const int tid = threadIdx.x;
    const int wv = tid >> 6, lane = tid & 63;
    const int l15 = lane & 15, q = lane >> 4;
    const int mrow = (wv >> 1) * 64, ncol = (wv & 1) * 64;
    const float decay = 1.f - (float)(*itp) / NITER_F;
    const float alpha = ALPHA0 * decay;
    const float sig = SIGMA0 * decay;
    const float inv = -1.f / (sig * sig);

    // count-conv for this jc column (S[ic] for all ic), fp32
    if (tid < 128) {
        float s = 0.f;
        for (int j = 0; j < 128; ++j) {
            const float dd = (float)(jc - j);
            s += __expf(dd * dd * inv) * cnt[tid * 128 + j];
        }
        cntHs[tid] = s;
    }
    {   // compute E tile in LDS
        const int row = tid >> 1, hh = tid & 1;
        _Float16* dst = Es + row * EP + hh * 64;
        #pragma unroll
        for (int u = 0; u < 64; ++u) {
            const float dd = (float)(row - hh * 64 - u);
            dst[u] = (_Float16)__expf(dd * dd * inv);
        }
    }
    __syncthreads();
    if (tid < 128) {
        float s = 0.f;
        for (int i = 0; i < 128; ++i) {
            const float dd = (float)(tid - i);
            s += __expf(dd * dd * inv) * cntHs[i];
        }
        Ss[tid] = s;
    }

    floatx4 acc[4][4];
    #pragma unroll
    for (int i = 0; i < 4; ++i)
        #pragma unroll
        for (int j = 0; j < 4; ++j) acc[i][j] = (floatx4){0.f, 0.f, 0.f, 0.f};

    const int dpo = (tid & 15) * 8;
    const int rsel = tid >> 4;
    for (int k0 = 0; k0 < 128; k0 += 32) {
        __syncthreads();
        #pragma unroll
        for (int s = 0; s < 2; ++s) {   // coalesced: 16 lanes read one row's 256B chunk
            const int i = k0 + s * 16 + rsel;
            const half8 v = *(const half8*)(Hh + (size_t)(i * 128 + jc) * 1536 + d0 * 2 + dpo);
            #pragma unroll
            for (int u = 0; u < 8; ++u)
                Bs[(dpo + u) * BP + (s * 16 + rsel)] = v[u];
        }
        __syncthreads();
        half8 af[4], bf[4];
        #pragma unroll
        for (int i = 0; i < 4; ++i)
            af[i] = *(const half8*)(Es + (mrow + i * 16 + l15) * EP + k0 + q * 8);
        #pragma unroll
        for (int j = 0; j < 4; ++j)
            bf[j] = *(const half8*)(Bs + (ncol + j * 16 + l15) * BP + q * 8);
        #pragma unroll
        for (int i = 0; i < 4; ++i)
            #pragma unroll
            for (int j = 0; j < 4; ++j)
                acc[i][j] = __builtin_amdgcn_mfma_f32_16x16x32_f16(af[i], bf[j], acc[i][j], 0, 0, 0);
    }
    __syncthreads();
    // fused epilogue: fp32 bounce in 2 chunks of 64 rows (m = ic)
    float* Ebf = (float*)Es;            // [64][132] floats
    #pragma unroll
    for (int ch = 0; ch < 2; ++ch) {
        if ((wv >> 1) == ch) {
            #pragma unroll
            for (int i = 0; i < 4; ++i)
                #pragma unroll
                for (int j = 0; j < 4; ++j)
                    #pragma unroll
                    for (int r = 0; r < 4; ++r)
                        Ebf[(i * 16 + q * 4 + r) * 132 + ncol + j * 16 + l15] = acc[i][j][r];
        }
        __syncthreads();
        {
            const int row = tid >> 2, seg = tid & 3;    // 64 rows x 4 segs of 32 floats
            const int m = ch * 64 + row;                // ic
            const int c = m * 128 + jc;
            const float scl = 1.f - alpha * Ss[m];
            const size_t g = (size_t)c * DIM + d0 + seg * 32;
            #pragma unroll
            for (int u = 0; u < 8; ++u) {
                float4 wv4 = *(const float4*)(w + g + u * 4);
                float4 t4  = *(const float4*)(Ebf + row * 132 + seg * 32 + u * 4);
                float4 o;
                o.x = wv4.x * scl + alpha * t4.x;
                o.y = wv4.y * scl + alpha * t4.y;
                o.z = wv4.z * scl + alpha * t4.z;
                o.w = wv4.w * scl + alpha * t4.w;
                *(float4*)(out + g + u * 4) = o;
            }
        }
        __syncthreads();
    }
}

extern "C" void kernel_launch(void* const* d_in, const int* in_sizes, int n_in,
                              void* d_out, int out_size, void* d_ws, size_t ws_size,
                              hipStream_t stream) {
    const float* x  = (const float*)d_in[0];   // [4096, 768]
    const float* w  = (const float*)d_in[1];   // [16384, 768]
    const int* itp  = (const int*)d_in[2];     // scalar it
    float* out = (float*)d_out;                // [16384, 768]
    char* ws = (char*)d_ws;

    _Float16* xh = (_Float16*)(ws + XH_OFF);
    _Float16* wh = (_Float16*)(ws + WH_OFF);
    float*    G  = (float*)(ws + G_OFF);       // aliases xh/wh, used post-bmu
    _Float16* Hh = (_Float16*)(ws + G_OFF);    // H fp16 chunk-packed inside G rows
    unsigned long long* best = (unsigned long long*)(ws + BEST_OFF);
    float* cnt  = (float*)(ws + CNT_OFF);
    float* wn2  = (float*)(ws + WN2_OFF);

    hipMemsetAsync(ws + BEST_OFF, 0, BEST_BYTES + CNT_BYTES, stream);

    cvt_kernel<<<(BS * DIM / 4 + 255) / 256, 256, 0, stream>>>(x, xh, BS * DIM / 4);
    cvtw_wn2_kernel<<<COMPS, 192, 0, stream>>>(w, wh, wn2);

    bmu_kernel<<<dim3(COMPS / 128, BS / 128), 256, 0, stream>>>(xh, wh, wn2, best);

    // xh/wh dead -> zero full G (stream-ordered after bmu)
    hipMemsetAsync(ws + G_OFF, 0, G_BYTES, stream);
    scatter_kernel<<<BS, 256, 0, stream>>>(best, x, G, cnt);

    // pass A: H fp16 (chunk-packed into G storage)
    convA_kernel<<<dim3(6, 128), 256, 0, stream>>>(G, Hh, itp);
    // pass B + count-conv + epilogue -> d_out
    convB_kernel<<<dim3(6, 128), 256, 0, stream>>>(Hh, w, cnt, itp, out);
}